// Round 1
// baseline (977.020 us; speedup 1.0000x reference)
//
#include <hip/hip_runtime.h>
#include <hip/hip_bf16.h>
#include <stdint.h>

#define D256 256

typedef short bf16x8 __attribute__((ext_vector_type(8)));
typedef float f32x4 __attribute__((ext_vector_type(4)));

static __device__ __forceinline__ unsigned short f32_to_bf16_bits(float f) {
    union { float f; uint32_t u; } v; v.f = f;
    uint32_t lsb = (v.u >> 16) & 1u;
    uint32_t r = v.u + 0x7fffu + lsb;
    return (unsigned short)(r >> 16);
}
static __device__ __forceinline__ float bf16_bits_to_f32(unsigned short u) {
    union { uint32_t u; float f; } v; v.u = ((uint32_t)u) << 16;
    return v.f;
}

// ---------------- degree count ----------------
__global__ void count_kernel(const int* __restrict__ col, int* __restrict__ cnt, int E) {
    int e = blockIdx.x * blockDim.x + threadIdx.x;
    if (e < E) atomicAdd(&cnt[col[e]], 1);
}

// ---------------- scan phase A: per-block exclusive scan (1024 elems/block) ----
__global__ void scanA_kernel(const int* __restrict__ cnt, int* __restrict__ off,
                             int* __restrict__ bsums, int N) {
    int tid = threadIdx.x;                 // 256 threads
    int b = blockIdx.x;
    int i0 = b * 1024 + tid * 4;
    int v0 = (i0 + 0 < N) ? cnt[i0 + 0] : 0;
    int v1 = (i0 + 1 < N) ? cnt[i0 + 1] : 0;
    int v2 = (i0 + 2 < N) ? cnt[i0 + 2] : 0;
    int v3 = (i0 + 3 < N) ? cnt[i0 + 3] : 0;
    int s = v0 + v1 + v2 + v3;
    int lane = tid & 63, wid = tid >> 6;
    int inc = s;
    for (int d = 1; d < 64; d <<= 1) {
        int o = __shfl_up(inc, d, 64);
        if (lane >= d) inc += o;
    }
    __shared__ int wt[4];
    if (lane == 63) wt[wid] = inc;
    __syncthreads();
    int wbase = 0;
    for (int k = 0; k < wid; k++) wbase += wt[k];
    int excl = wbase + inc - s;
    if (i0 + 0 < N) off[i0 + 0] = excl;
    if (i0 + 1 < N) off[i0 + 1] = excl + v0;
    if (i0 + 2 < N) off[i0 + 2] = excl + v0 + v1;
    if (i0 + 3 < N) off[i0 + 3] = excl + v0 + v1 + v2;
    if (tid == 255) bsums[b] = wbase + inc;
}

// ---------------- scan phase B: scan the <=64 block sums ----------------
__global__ void scanB_kernel(const int* __restrict__ bsums, int* __restrict__ bbase, int nb) {
    int t = threadIdx.x;                   // 64 threads
    int s = (t < nb) ? bsums[t] : 0;
    int inc = s;
    for (int d = 1; d < 64; d <<= 1) {
        int o = __shfl_up(inc, d, 64);
        if (t >= d) inc += o;
    }
    if (t < nb) bbase[t] = inc - s;        // exclusive
}

// ---------------- scan phase C: add base, init cursor, dis ----------------
__global__ void scanC_kernel(int* __restrict__ off, int* __restrict__ cursor,
                             float* __restrict__ dis, const int* __restrict__ cnt,
                             const int* __restrict__ bbase, int N, int E) {
    int i = blockIdx.x * blockDim.x + threadIdx.x;
    if (i < N) {
        int o = off[i] + bbase[i >> 10];
        off[i] = o;
        cursor[i] = o;
        dis[i] = rsqrtf((float)(cnt[i] + 1));   // +1 self loop; always > 0
    }
    if (i == 0) off[N] = E;
}

// ---------------- bucket edges by target ----------------
__global__ void scatter_kernel(const int* __restrict__ ei, int* __restrict__ cursor,
                               int* __restrict__ srow, int E) {
    int e = blockIdx.x * blockDim.x + threadIdx.x;
    if (e < E) {
        int r = ei[e];
        int c = ei[E + e];
        int p = atomicAdd(&cursor[c], 1);
        srow[p] = r;
    }
}

// ---------------- pack W into MFMA B-fragment layout (bf16) ----------------
// Wb[((k>>3)*256 + n)*8 + (k&7)] = bf16(W[k][n])
__global__ void wprep_kernel(const float* __restrict__ W, unsigned short* __restrict__ Wb) {
    int e = blockIdx.x * blockDim.x + threadIdx.x;  // < 65536
    int k = e >> 8, n = e & 255;
    Wb[(((k >> 3) * 256 + n) << 3) + (k & 7)] = f32_to_bf16_bits(W[e]);
}

// ---------------- h = x @ W  (bf16 MFMA, h stored bf16) ----------------
__global__ __launch_bounds__(256) void gemm_kernel(const float* __restrict__ x,
                                                   const unsigned short* __restrict__ Wb,
                                                   unsigned short* __restrict__ h, int N) {
    int tid = threadIdx.x;
    int lane = tid & 63;
    int w = tid >> 6;                 // wave 0..3 -> col block
    int l15 = lane & 15, l4 = lane >> 4;
    int m0 = blockIdx.x * 64;
    int colbase = w * 64;

    f32x4 acc[4][4];
    for (int mi = 0; mi < 4; mi++)
        for (int ni = 0; ni < 4; ni++)
            acc[mi][ni] = (f32x4){0.f, 0.f, 0.f, 0.f};

    for (int kk = 0; kk < 8; kk++) {
        int k0 = kk * 32 + l4 * 8;
        bf16x8 a[4], bb[4];
        for (int mi = 0; mi < 4; mi++) {
            int row = m0 + mi * 16 + l15;
            if (row >= N) row = N - 1;          // clamp (padded rows not stored)
            const float* xp = x + row * 256 + k0;
            float4 x0 = *(const float4*)xp;
            float4 x1 = *(const float4*)(xp + 4);
            a[mi][0] = (short)f32_to_bf16_bits(x0.x);
            a[mi][1] = (short)f32_to_bf16_bits(x0.y);
            a[mi][2] = (short)f32_to_bf16_bits(x0.z);
            a[mi][3] = (short)f32_to_bf16_bits(x0.w);
            a[mi][4] = (short)f32_to_bf16_bits(x1.x);
            a[mi][5] = (short)f32_to_bf16_bits(x1.y);
            a[mi][6] = (short)f32_to_bf16_bits(x1.z);
            a[mi][7] = (short)f32_to_bf16_bits(x1.w);
        }
        int kc = kk * 4 + l4;
        for (int ni = 0; ni < 4; ni++) {
            int n = colbase + ni * 16 + l15;
            bb[ni] = *(const bf16x8*)(Wb + (((kc << 8) + n) << 3));
        }
        for (int mi = 0; mi < 4; mi++)
            for (int ni = 0; ni < 4; ni++)
                acc[mi][ni] = __builtin_amdgcn_mfma_f32_16x16x32_bf16(a[mi], bb[ni], acc[mi][ni], 0, 0, 0);
    }

    for (int mi = 0; mi < 4; mi++) {
        for (int ni = 0; ni < 4; ni++) {
            int cn = colbase + ni * 16 + l15;
            for (int v = 0; v < 4; v++) {
                int row = m0 + mi * 16 + l4 * 4 + v;
                if (row < N) h[row * 256 + cn] = f32_to_bf16_bits(acc[mi][ni][v]);
            }
        }
    }
}

// ---------------- aggregate + sigmoid + partial column-mean ----------------
// wave per node (grid-strided); per-block partial column sums -> partials[blk][256]
__global__ __launch_bounds__(256) void agg_kernel(const unsigned short* __restrict__ h,
                                                  const int* __restrict__ off,
                                                  const int* __restrict__ srow,
                                                  const float* __restrict__ dis,
                                                  const float* __restrict__ bconv,
                                                  float* __restrict__ partials, int N) {
    int lane = threadIdx.x & 63, wid = threadIdx.x >> 6;
    int d0 = lane * 4;
    float4 bc = *(const float4*)(bconv + d0);
    int gw = blockIdx.x * 4 + wid;
    int stride = gridDim.x * 4;

    float m0 = 0.f, m1 = 0.f, m2 = 0.f, m3 = 0.f;
    for (int c = gw; c < N; c += stride) {
        float dc = dis[c];
        // self loop term: dis[c] * h[c]
        ushort4 hs = *(const ushort4*)(h + c * 256 + d0);
        float a0 = dc * bf16_bits_to_f32(hs.x);
        float a1 = dc * bf16_bits_to_f32(hs.y);
        float a2 = dc * bf16_bits_to_f32(hs.z);
        float a3 = dc * bf16_bits_to_f32(hs.w);
        int j1 = off[c + 1];
        for (int j = off[c]; j < j1; j++) {
            int r = srow[j];
            float wr = dis[r];
            ushort4 e = *(const ushort4*)(h + r * 256 + d0);
            a0 += wr * bf16_bits_to_f32(e.x);
            a1 += wr * bf16_bits_to_f32(e.y);
            a2 += wr * bf16_bits_to_f32(e.z);
            a3 += wr * bf16_bits_to_f32(e.w);
        }
        a0 = a0 * dc + bc.x;
        a1 = a1 * dc + bc.y;
        a2 = a2 * dc + bc.z;
        a3 = a3 * dc + bc.w;
        m0 += 1.f / (1.f + __expf(-a0));
        m1 += 1.f / (1.f + __expf(-a1));
        m2 += 1.f / (1.f + __expf(-a2));
        m3 += 1.f / (1.f + __expf(-a3));
    }
    __shared__ float red[4][256];
    red[wid][d0 + 0] = m0; red[wid][d0 + 1] = m1;
    red[wid][d0 + 2] = m2; red[wid][d0 + 3] = m3;
    __syncthreads();
    if (wid == 0) {
        for (int t = 0; t < 4; t++) {
            int d = d0 + t;
            partials[blockIdx.x * 256 + d] = red[0][d] + red[1][d] + red[2][d] + red[3][d];
        }
    }
}

// ---------------- reduce partials: 2048 rows -> 32 rows ----------------
__global__ void reduceA_kernel(const float* __restrict__ partials, float* __restrict__ p2) {
    int d = threadIdx.x;                   // 256
    int b = blockIdx.x;                    // 32
    float s = 0.f;
    int r0 = b * 64;
    for (int r = r0; r < r0 + 64; r++) s += partials[r * 256 + d];
    p2[b * 256 + d] = s;
}

// ---------------- final: mean, dot with w_lin, sigmoid ----------------
__global__ void final_kernel(const float* __restrict__ p2, const float* __restrict__ wlin,
                             const float* __restrict__ blin, float* __restrict__ out, int N) {
    int d = threadIdx.x;                   // 256
    float s = 0.f;
    for (int b = 0; b < 32; b++) s += p2[b * 256 + d];
    float x3 = s / (float)N;
    float t = x3 * wlin[d];
    __shared__ float red[256];
    red[d] = t;
    __syncthreads();
    for (int st = 128; st > 0; st >>= 1) {
        if (d < st) red[d] += red[d + st];
        __syncthreads();
    }
    if (d == 0) out[0] = 1.f / (1.f + expf(-(red[0] + blin[0])));
}

extern "C" void kernel_launch(void* const* d_in, const int* in_sizes, int n_in,
                              void* d_out, int out_size, void* d_ws, size_t ws_size,
                              hipStream_t stream) {
    const float* x     = (const float*)d_in[0];
    const int*   ei    = (const int*)d_in[1];     // [2][E] int (harness delivers ints as int32)
    const float* W     = (const float*)d_in[2];
    const float* bconv = (const float*)d_in[3];
    const float* wlin  = (const float*)d_in[4];
    const float* blin  = (const float*)d_in[5];
    float* out = (float*)d_out;

    int N = in_sizes[0] / 256;
    int E = in_sizes[1] / 2;

    char* ws = (char*)d_ws;
    size_t o = 0;
    auto alloc = [&](size_t bytes) -> char* {
        char* p = ws + o;
        o = (o + bytes + 255) & ~(size_t)255;
        return p;
    };
    int*   cnt     = (int*)alloc((size_t)N * 4);
    int*   off     = (int*)alloc((size_t)(N + 1) * 4);
    int*   cursor  = (int*)alloc((size_t)N * 4);
    float* dis     = (float*)alloc((size_t)N * 4);
    int*   bsums   = (int*)alloc(64 * 4);
    int*   bbase   = (int*)alloc(64 * 4);
    int*   srow    = (int*)alloc((size_t)E * 4);
    unsigned short* Wb = (unsigned short*)alloc(65536 * 2);
    unsigned short* h  = (unsigned short*)alloc((size_t)N * 256 * 2);
    float* partials = (float*)alloc(2048 * 256 * 4);
    float* p2       = (float*)alloc(32 * 256 * 4);

    hipMemsetAsync(cnt, 0, (size_t)N * 4, stream);

    int eb = (E + 255) / 256;
    count_kernel<<<eb, 256, 0, stream>>>(ei + E, cnt, E);

    int nbA = (N + 1023) / 1024;
    scanA_kernel<<<nbA, 256, 0, stream>>>(cnt, off, bsums, N);
    scanB_kernel<<<1, 64, 0, stream>>>(bsums, bbase, nbA);
    scanC_kernel<<<(N + 255) / 256, 256, 0, stream>>>(off, cursor, dis, cnt, bbase, N, E);
    scatter_kernel<<<eb, 256, 0, stream>>>(ei, cursor, srow, E);

    wprep_kernel<<<65536 / 256, 256, 0, stream>>>(W, Wb);
    gemm_kernel<<<(N + 63) / 64, 256, 0, stream>>>(x, Wb, h, N);

    agg_kernel<<<2048, 256, 0, stream>>>(h, off, srow, dis, bconv, partials, N);
    reduceA_kernel<<<32, 256, 0, stream>>>(partials, p2);
    final_kernel<<<1, 256, 0, stream>>>(p2, wlin, blin, out, N);
}

// Round 12
// 291.874 us; speedup vs baseline: 3.3474x; 3.3474x over previous
//
#include <hip/hip_runtime.h>
#include <hip/hip_bf16.h>
#include <stdint.h>

typedef short bf16x8 __attribute__((ext_vector_type(8)));
typedef unsigned short u16x8 __attribute__((ext_vector_type(8)));
typedef float f32x4 __attribute__((ext_vector_type(4)));

static __device__ __forceinline__ unsigned short f32_to_bf16_bits(float f) {
    union { float f; uint32_t u; } v; v.f = f;
    uint32_t lsb = (v.u >> 16) & 1u;
    uint32_t r = v.u + 0x7fffu + lsb;
    return (unsigned short)(r >> 16);
}
static __device__ __forceinline__ float bf16_bits_to_f32(unsigned short u) {
    union { uint32_t u; float f; } v; v.u = ((uint32_t)u) << 16;
    return v.f;
}

// ---------------- degree count ----------------
__global__ void count_kernel(const int* __restrict__ col, int* __restrict__ cnt, int E) {
    int e = blockIdx.x * blockDim.x + threadIdx.x;
    if (e < E) atomicAdd(&cnt[col[e]], 1);
}

// ---------------- scan phase A ----------------
__global__ void scanA_kernel(const int* __restrict__ cnt, int* __restrict__ off,
                             int* __restrict__ bsums, int N) {
    int tid = threadIdx.x;                 // 256 threads
    int b = blockIdx.x;
    int i0 = b * 1024 + tid * 4;
    int v0 = (i0 + 0 < N) ? cnt[i0 + 0] : 0;
    int v1 = (i0 + 1 < N) ? cnt[i0 + 1] : 0;
    int v2 = (i0 + 2 < N) ? cnt[i0 + 2] : 0;
    int v3 = (i0 + 3 < N) ? cnt[i0 + 3] : 0;
    int s = v0 + v1 + v2 + v3;
    int lane = tid & 63, wid = tid >> 6;
    int inc = s;
    for (int d = 1; d < 64; d <<= 1) {
        int o = __shfl_up(inc, d, 64);
        if (lane >= d) inc += o;
    }
    __shared__ int wt[4];
    if (lane == 63) wt[wid] = inc;
    __syncthreads();
    int wbase = 0;
    for (int k = 0; k < wid; k++) wbase += wt[k];
    int excl = wbase + inc - s;
    if (i0 + 0 < N) off[i0 + 0] = excl;
    if (i0 + 1 < N) off[i0 + 1] = excl + v0;
    if (i0 + 2 < N) off[i0 + 2] = excl + v0 + v1;
    if (i0 + 3 < N) off[i0 + 3] = excl + v0 + v1 + v2;
    if (tid == 255) bsums[b] = wbase + inc;
}

// ---------------- scan phase B ----------------
__global__ void scanB_kernel(const int* __restrict__ bsums, int* __restrict__ bbase, int nb) {
    int t = threadIdx.x;                   // 64 threads
    int s = (t < nb) ? bsums[t] : 0;
    int inc = s;
    for (int d = 1; d < 64; d <<= 1) {
        int o = __shfl_up(inc, d, 64);
        if (t >= d) inc += o;
    }
    if (t < nb) bbase[t] = inc - s;        // exclusive
}

// ---------------- scan phase C ----------------
__global__ void scanC_kernel(int* __restrict__ off, int* __restrict__ cursor,
                             float* __restrict__ dis, const int* __restrict__ cnt,
                             const int* __restrict__ bbase, int N, int E) {
    int i = blockIdx.x * blockDim.x + threadIdx.x;
    if (i < N) {
        int o = off[i] + bbase[i >> 10];
        off[i] = o;
        cursor[i] = o;
        dis[i] = rsqrtf((float)(cnt[i] + 1));   // +1 self loop
    }
    if (i == 0) off[N] = E;
}

// ---------------- bucket edges by target ----------------
__global__ void scatter_kernel(const int* __restrict__ ei, int* __restrict__ cursor,
                               int* __restrict__ srow, int E) {
    int e = blockIdx.x * blockDim.x + threadIdx.x;
    if (e < E) {
        int r = ei[e];
        int c = ei[E + e];
        int p = atomicAdd(&cursor[c], 1);
        srow[p] = r;
    }
}

// ---------------- x (f32) -> xb (bf16) ----------------
__global__ __launch_bounds__(256) void xconv_kernel(const float* __restrict__ x,
                                                    unsigned short* __restrict__ xb, int total8) {
    int stride = gridDim.x * blockDim.x;
    for (int i = blockIdx.x * blockDim.x + threadIdx.x; i < total8; i += stride) {
        const float* p = x + (size_t)i * 8;
        float4 a = *(const float4*)p;
        float4 b = *(const float4*)(p + 4);
        u16x8 o;
        o[0] = f32_to_bf16_bits(a.x); o[1] = f32_to_bf16_bits(a.y);
        o[2] = f32_to_bf16_bits(a.z); o[3] = f32_to_bf16_bits(a.w);
        o[4] = f32_to_bf16_bits(b.x); o[5] = f32_to_bf16_bits(b.y);
        o[6] = f32_to_bf16_bits(b.z); o[7] = f32_to_bf16_bits(b.w);
        *(u16x8*)(xb + (size_t)i * 8) = o;
    }
}

// ---------------- pack W into MFMA B-fragment layout ----------------
__global__ void wprep_kernel(const float* __restrict__ W, unsigned short* __restrict__ Wb) {
    int e = blockIdx.x * blockDim.x + threadIdx.x;  // < 65536
    int k = e >> 8, n = e & 255;
    Wb[(((k >> 3) * 256 + n) << 3) + (k & 7)] = f32_to_bf16_bits(W[e]);
}

// ---------------- h = xb @ W  (bf16 MFMA) ----------------
// block: 64 rows x 256 cols; 4 waves, wave w owns cols w*64..w*64+63
__global__ __launch_bounds__(256) void gemm_kernel(const unsigned short* __restrict__ xb,
                                                   const unsigned short* __restrict__ Wb,
                                                   unsigned short* __restrict__ h, int N) {
    int tid = threadIdx.x;
    int lane = tid & 63;
    int w = tid >> 6;
    int l15 = lane & 15, l4 = lane >> 4;
    int m0 = blockIdx.x * 64;
    int colbase = w * 64;

    f32x4 acc[4][4];
    for (int mi = 0; mi < 4; mi++)
        for (int ni = 0; ni < 4; ni++)
            acc[mi][ni] = (f32x4){0.f, 0.f, 0.f, 0.f};

    for (int kk = 0; kk < 8; kk++) {
        bf16x8 a[4], bb[4];
        int k0 = kk * 32 + l4 * 8;
        for (int mi = 0; mi < 4; mi++) {
            int row = m0 + mi * 16 + l15;
            if (row >= N) row = N - 1;
            a[mi] = *(const bf16x8*)(xb + (size_t)row * 256 + k0);
        }
        int kc = kk * 4 + l4;
        for (int ni = 0; ni < 4; ni++) {
            int n = colbase + ni * 16 + l15;
            bb[ni] = *(const bf16x8*)(Wb + (((kc << 8) + n) << 3));
        }
        for (int mi = 0; mi < 4; mi++)
            for (int ni = 0; ni < 4; ni++)
                acc[mi][ni] = __builtin_amdgcn_mfma_f32_16x16x32_bf16(a[mi], bb[ni], acc[mi][ni], 0, 0, 0);
    }

    // epilogue: transpose via LDS (stride 72 ushorts, conflict-light), store dwordx4
    __shared__ unsigned short tile[4 * 64 * 72];
    unsigned short* tw = tile + w * 64 * 72;
    for (int mi = 0; mi < 4; mi++)
        for (int ni = 0; ni < 4; ni++)
            for (int v = 0; v < 4; v++)
                tw[(mi * 16 + l4 * 4 + v) * 72 + ni * 16 + l15] = f32_to_bf16_bits(acc[mi][ni][v]);
    __builtin_amdgcn_s_waitcnt(0);  // lgkm drain (same-wave LDS RAW; compiler also inserts)
    for (int t = 0; t < 8; t++) {
        int row_r = t * 8 + (lane >> 3);
        int col_r = (lane & 7) * 8;
        int gr = m0 + row_r;
        if (gr < N) {
            u16x8 vv = *(const u16x8*)(tw + row_r * 72 + col_r);
            *(u16x8*)(h + (size_t)gr * 256 + colbase + col_r) = vv;
        }
    }
}

// ---------------- aggregate + sigmoid + partial column-mean ----------------
// one wave per node (grid-strided); two edges in flight (halves of the wave);
// each lane covers 8 columns via bf16x8 loads.
__global__ __launch_bounds__(256) void agg_kernel(const unsigned short* __restrict__ h,
                                                  const int* __restrict__ off,
                                                  const int* __restrict__ srow,
                                                  const float* __restrict__ dis,
                                                  const float* __restrict__ bconv,
                                                  float* __restrict__ partials, int N) {
    int lane = threadIdx.x & 63, wid = threadIdx.x >> 6;
    int hi = lane >> 5;
    int l5 = lane & 31;
    int c8 = l5 * 8;                        // 8 columns per lane
    float bc[8];
    {
        float4 b0 = *(const float4*)(bconv + c8);
        float4 b1 = *(const float4*)(bconv + c8 + 4);
        bc[0]=b0.x; bc[1]=b0.y; bc[2]=b0.z; bc[3]=b0.w;
        bc[4]=b1.x; bc[5]=b1.y; bc[6]=b1.z; bc[7]=b1.w;
    }
    int gw = blockIdx.x * 4 + wid;
    int stride = gridDim.x * 4;

    float m[8];
    for (int k = 0; k < 8; k++) m[k] = 0.f;

    for (int c = gw; c < N; c += stride) {
        float dc = dis[c];
        float a[8];
        // self loop with 0.5 weight in both halves (combine doubles it)
        {
            float half_dc = 0.5f * dc;
            bf16x8 e = *(const bf16x8*)(h + (size_t)c * 256 + c8);
            for (int k = 0; k < 8; k++) a[k] = half_dc * bf16_bits_to_f32((unsigned short)e[k]);
        }
        int j1 = off[c + 1];
        for (int j = off[c] + hi; j < j1; j += 2) {
            int r = srow[j];
            float wr = dis[r];
            bf16x8 e = *(const bf16x8*)(h + (size_t)r * 256 + c8);
            for (int k = 0; k < 8; k++) a[k] += wr * bf16_bits_to_f32((unsigned short)e[k]);
        }
        for (int k = 0; k < 8; k++) {
            float comb = a[k] + __shfl_xor(a[k], 32);
            float val = comb * dc + bc[k];
            m[k] += 1.f / (1.f + __expf(-val));
        }
    }
    __shared__ float red[4][256];
    if (hi == 0)
        for (int k = 0; k < 8; k++) red[wid][c8 + k] = m[k];
    __syncthreads();
    int d = threadIdx.x;
    partials[(size_t)blockIdx.x * 256 + d] = red[0][d] + red[1][d] + red[2][d] + red[3][d];
}

// ---------------- reduce partials: 2048 rows -> 32 rows ----------------
__global__ void reduceA_kernel(const float* __restrict__ partials, float* __restrict__ p2) {
    int d = threadIdx.x;
    int b = blockIdx.x;
    float s = 0.f;
    int r0 = b * 64;
    for (int r = r0; r < r0 + 64; r++) s += partials[r * 256 + d];
    p2[b * 256 + d] = s;
}

// ---------------- final ----------------
__global__ void final_kernel(const float* __restrict__ p2, const float* __restrict__ wlin,
                             const float* __restrict__ blin, float* __restrict__ out, int N) {
    int d = threadIdx.x;
    float s = 0.f;
    for (int b = 0; b < 32; b++) s += p2[b * 256 + d];
    float x3 = s / (float)N;
    float t = x3 * wlin[d];
    __shared__ float red[256];
    red[d] = t;
    __syncthreads();
    for (int st = 128; st > 0; st >>= 1) {
        if (d < st) red[d] += red[d + st];
        __syncthreads();
    }
    if (d == 0) out[0] = 1.f / (1.f + expf(-(red[0] + blin[0])));
}

extern "C" void kernel_launch(void* const* d_in, const int* in_sizes, int n_in,
                              void* d_out, int out_size, void* d_ws, size_t ws_size,
                              hipStream_t stream) {
    const float* x     = (const float*)d_in[0];
    const int*   ei    = (const int*)d_in[1];
    const float* W     = (const float*)d_in[2];
    const float* bconv = (const float*)d_in[3];
    const float* wlin  = (const float*)d_in[4];
    const float* blin  = (const float*)d_in[5];
    float* out = (float*)d_out;

    int N = in_sizes[0] / 256;
    int E = in_sizes[1] / 2;

    char* ws = (char*)d_ws;
    size_t o = 0;
    auto alloc = [&](size_t bytes) -> char* {
        char* p = ws + o;
        o = (o + bytes + 255) & ~(size_t)255;
        return p;
    };
    int*   cnt     = (int*)alloc((size_t)N * 4);
    int*   off     = (int*)alloc((size_t)(N + 1) * 4);
    int*   cursor  = (int*)alloc((size_t)N * 4);
    float* dis     = (float*)alloc((size_t)N * 4);
    int*   bsums   = (int*)alloc(64 * 4);
    int*   bbase   = (int*)alloc(64 * 4);
    int*   srow    = (int*)alloc((size_t)E * 4);
    unsigned short* Wb = (unsigned short*)alloc(65536 * 2);
    unsigned short* xb = (unsigned short*)alloc((size_t)N * 256 * 2);
    unsigned short* h  = (unsigned short*)alloc((size_t)N * 256 * 2);
    float* partials = (float*)alloc(2048 * 256 * 4);
    float* p2       = (float*)alloc(32 * 256 * 4);

    hipMemsetAsync(cnt, 0, (size_t)N * 4, stream);

    int eb = (E + 255) / 256;
    count_kernel<<<eb, 256, 0, stream>>>(ei + E, cnt, E);

    int nbA = (N + 1023) / 1024;
    scanA_kernel<<<nbA, 256, 0, stream>>>(cnt, off, bsums, N);
    scanB_kernel<<<1, 64, 0, stream>>>(bsums, bbase, nbA);
    scanC_kernel<<<(N + 255) / 256, 256, 0, stream>>>(off, cursor, dis, cnt, bbase, N, E);
    scatter_kernel<<<eb, 256, 0, stream>>>(ei, cursor, srow, E);

    xconv_kernel<<<1024, 256, 0, stream>>>(x, xb, N * 256 / 8);
    wprep_kernel<<<65536 / 256, 256, 0, stream>>>(W, Wb);
    gemm_kernel<<<(N + 63) / 64, 256, 0, stream>>>(xb, Wb, h, N);

    agg_kernel<<<2048, 256, 0, stream>>>(h, off, srow, dis, bconv, partials, N);
    reduceA_kernel<<<32, 256, 0, stream>>>(partials, p2);
    final_kernel<<<1, 256, 0, stream>>>(p2, wlin, blin, out, N);
}

// Round 13
// 289.875 us; speedup vs baseline: 3.3705x; 1.0069x over previous
//
#include <hip/hip_runtime.h>
#include <hip/hip_bf16.h>
#include <stdint.h>

typedef short bf16x8 __attribute__((ext_vector_type(8)));
typedef unsigned short u16x8 __attribute__((ext_vector_type(8)));
typedef float f32x4 __attribute__((ext_vector_type(4)));

static __device__ __forceinline__ unsigned short f32_to_bf16_bits(float f) {
    union { float f; uint32_t u; } v; v.f = f;
    uint32_t lsb = (v.u >> 16) & 1u;
    uint32_t r = v.u + 0x7fffu + lsb;
    return (unsigned short)(r >> 16);
}
static __device__ __forceinline__ float bf16_bits_to_f32(unsigned short u) {
    union { uint32_t u; float f; } v; v.u = ((uint32_t)u) << 16;
    return v.f;
}

// ---------------- degree count ----------------
__global__ void count_kernel(const int* __restrict__ col, int* __restrict__ cnt, int E) {
    int e = blockIdx.x * blockDim.x + threadIdx.x;
    if (e < E) atomicAdd(&cnt[col[e]], 1);
}

// ---------------- scan phase A ----------------
__global__ void scanA_kernel(const int* __restrict__ cnt, int* __restrict__ off,
                             int* __restrict__ bsums, int N) {
    int tid = threadIdx.x;                 // 256 threads
    int b = blockIdx.x;
    int i0 = b * 1024 + tid * 4;
    int v0 = (i0 + 0 < N) ? cnt[i0 + 0] : 0;
    int v1 = (i0 + 1 < N) ? cnt[i0 + 1] : 0;
    int v2 = (i0 + 2 < N) ? cnt[i0 + 2] : 0;
    int v3 = (i0 + 3 < N) ? cnt[i0 + 3] : 0;
    int s = v0 + v1 + v2 + v3;
    int lane = tid & 63, wid = tid >> 6;
    int inc = s;
    for (int d = 1; d < 64; d <<= 1) {
        int o = __shfl_up(inc, d, 64);
        if (lane >= d) inc += o;
    }
    __shared__ int wt[4];
    if (lane == 63) wt[wid] = inc;
    __syncthreads();
    int wbase = 0;
    for (int k = 0; k < wid; k++) wbase += wt[k];
    int excl = wbase + inc - s;
    if (i0 + 0 < N) off[i0 + 0] = excl;
    if (i0 + 1 < N) off[i0 + 1] = excl + v0;
    if (i0 + 2 < N) off[i0 + 2] = excl + v0 + v1;
    if (i0 + 3 < N) off[i0 + 3] = excl + v0 + v1 + v2;
    if (tid == 255) bsums[b] = wbase + inc;
}

// ---------------- scan phase B ----------------
__global__ void scanB_kernel(const int* __restrict__ bsums, int* __restrict__ bbase, int nb) {
    int t = threadIdx.x;                   // 64 threads
    int s = (t < nb) ? bsums[t] : 0;
    int inc = s;
    for (int d = 1; d < 64; d <<= 1) {
        int o = __shfl_up(inc, d, 64);
        if (t >= d) inc += o;
    }
    if (t < nb) bbase[t] = inc - s;        // exclusive
}

// ---------------- scan phase C ----------------
__global__ void scanC_kernel(int* __restrict__ off, int* __restrict__ cursor,
                             float* __restrict__ dis, const int* __restrict__ cnt,
                             const int* __restrict__ bbase, int N, int E) {
    int i = blockIdx.x * blockDim.x + threadIdx.x;
    if (i < N) {
        int o = off[i] + bbase[i >> 10];
        off[i] = o;
        cursor[i] = o;
        dis[i] = rsqrtf((float)(cnt[i] + 1));   // +1 self loop
    }
    if (i == 0) off[N] = E;
}

// ---------------- bucket edges by target ----------------
__global__ void scatter_kernel(const int* __restrict__ ei, int* __restrict__ cursor,
                               int* __restrict__ srow, int E) {
    int e = blockIdx.x * blockDim.x + threadIdx.x;
    if (e < E) {
        int r = ei[e];
        int c = ei[E + e];
        int p = atomicAdd(&cursor[c], 1);
        srow[p] = r;
    }
}

// ---------------- x (f32) -> xb (bf16) ----------------
__global__ __launch_bounds__(256) void xconv_kernel(const float* __restrict__ x,
                                                    unsigned short* __restrict__ xb, int total8) {
    int stride = gridDim.x * blockDim.x;
    for (int i = blockIdx.x * blockDim.x + threadIdx.x; i < total8; i += stride) {
        const float* p = x + (size_t)i * 8;
        float4 a = *(const float4*)p;
        float4 b = *(const float4*)(p + 4);
        u16x8 o;
        o[0] = f32_to_bf16_bits(a.x); o[1] = f32_to_bf16_bits(a.y);
        o[2] = f32_to_bf16_bits(a.z); o[3] = f32_to_bf16_bits(a.w);
        o[4] = f32_to_bf16_bits(b.x); o[5] = f32_to_bf16_bits(b.y);
        o[6] = f32_to_bf16_bits(b.z); o[7] = f32_to_bf16_bits(b.w);
        *(u16x8*)(xb + (size_t)i * 8) = o;
    }
}

// ---------------- pack W into MFMA B-fragment layout ----------------
__global__ void wprep_kernel(const float* __restrict__ W, unsigned short* __restrict__ Wb) {
    int e = blockIdx.x * blockDim.x + threadIdx.x;  // < 65536
    int k = e >> 8, n = e & 255;
    Wb[(((k >> 3) * 256 + n) << 3) + (k & 7)] = f32_to_bf16_bits(W[e]);
}

// ---------------- h' = dis[row] * (xb @ W)  (bf16 MFMA, pre-scaled rows) ----------------
// block: 64 rows x 256 cols; 4 waves, wave w owns cols w*64..w*64+63
__global__ __launch_bounds__(256) void gemm_kernel(const unsigned short* __restrict__ xb,
                                                   const unsigned short* __restrict__ Wb,
                                                   const float* __restrict__ dis,
                                                   unsigned short* __restrict__ h, int N) {
    int tid = threadIdx.x;
    int lane = tid & 63;
    int w = tid >> 6;
    int l15 = lane & 15, l4 = lane >> 4;
    int m0 = blockIdx.x * 64;
    int colbase = w * 64;

    f32x4 acc[4][4];
    for (int mi = 0; mi < 4; mi++)
        for (int ni = 0; ni < 4; ni++)
            acc[mi][ni] = (f32x4){0.f, 0.f, 0.f, 0.f};

    for (int kk = 0; kk < 8; kk++) {
        bf16x8 a[4], bb[4];
        int k0 = kk * 32 + l4 * 8;
        for (int mi = 0; mi < 4; mi++) {
            int row = m0 + mi * 16 + l15;
            if (row >= N) row = N - 1;
            a[mi] = *(const bf16x8*)(xb + (size_t)row * 256 + k0);
        }
        int kc = kk * 4 + l4;
        for (int ni = 0; ni < 4; ni++) {
            int n = colbase + ni * 16 + l15;
            bb[ni] = *(const bf16x8*)(Wb + (((kc << 8) + n) << 3));
        }
        for (int mi = 0; mi < 4; mi++)
            for (int ni = 0; ni < 4; ni++)
                acc[mi][ni] = __builtin_amdgcn_mfma_f32_16x16x32_bf16(a[mi], bb[ni], acc[mi][ni], 0, 0, 0);
    }

    // epilogue: scale by dis[row], transpose via LDS (stride 72), store dwordx4
    __shared__ unsigned short tile[4 * 64 * 72];
    unsigned short* tw = tile + w * 64 * 72;
    for (int mi = 0; mi < 4; mi++) {
        float dsc[4];
        for (int v = 0; v < 4; v++) {
            int rr = m0 + mi * 16 + l4 * 4 + v;
            dsc[v] = dis[rr < N ? rr : N - 1];
        }
        for (int ni = 0; ni < 4; ni++)
            for (int v = 0; v < 4; v++)
                tw[(mi * 16 + l4 * 4 + v) * 72 + ni * 16 + l15] =
                    f32_to_bf16_bits(acc[mi][ni][v] * dsc[v]);
    }
    __builtin_amdgcn_s_waitcnt(0);  // lgkm drain (same-wave LDS RAW)
    for (int t = 0; t < 8; t++) {
        int row_r = t * 8 + (lane >> 3);
        int col_r = (lane & 7) * 8;
        int gr = m0 + row_r;
        if (gr < N) {
            u16x8 vv = *(const u16x8*)(tw + row_r * 72 + col_r);
            *(u16x8*)(h + (size_t)gr * 256 + colbase + col_r) = vv;
        }
    }
}

// ---------------- aggregate + sigmoid + partial column-mean ----------------
// one wave per node; 4 groups of 16 lanes each handle edges j≡g (mod 4),
// 2x unrolled with dual accumulators => 8 gathers in flight per wave.
// lane covers 16 cols; h rows are pre-scaled by dis[src] in gemm.
__global__ __launch_bounds__(256) void agg_kernel(const unsigned short* __restrict__ h,
                                                  const int* __restrict__ off,
                                                  const int* __restrict__ srow,
                                                  const float* __restrict__ dis,
                                                  const float* __restrict__ bconv,
                                                  float* __restrict__ partials, int N) {
    int lane = threadIdx.x & 63, wid = threadIdx.x >> 6;
    int g = lane >> 4;                     // group 0..3
    int q = lane & 15;
    int c16 = q * 16;                      // 16 columns per lane
    float4 bc = *(const float4*)(bconv + c16 + g * 4);

    int gw = blockIdx.x * 4 + wid;
    int stride = gridDim.x * 4;

    float m[4] = {0.f, 0.f, 0.f, 0.f};

    for (int c = gw; c < N; c += stride) {
        float dc = dis[c];
        float a[16], b[16];
        {
            // self loop: h'[c] (only group 0 contributes)
            const unsigned short* hp = h + (size_t)c * 256 + c16;
            bf16x8 e0 = *(const bf16x8*)hp;
            bf16x8 e1 = *(const bf16x8*)(hp + 8);
            float sel = (g == 0) ? 1.f : 0.f;
            for (int k = 0; k < 8; k++) {
                a[k]     = sel * bf16_bits_to_f32((unsigned short)e0[k]);
                a[k + 8] = sel * bf16_bits_to_f32((unsigned short)e1[k]);
                b[k] = 0.f; b[k + 8] = 0.f;
            }
        }
        int j1 = off[c + 1];
        int j = off[c] + g;
        for (; j + 4 < j1; j += 8) {
            int r0 = srow[j];
            int r1 = srow[j + 4];
            const unsigned short* p0 = h + (size_t)r0 * 256 + c16;
            const unsigned short* p1 = h + (size_t)r1 * 256 + c16;
            bf16x8 e0 = *(const bf16x8*)p0;
            bf16x8 e1 = *(const bf16x8*)(p0 + 8);
            bf16x8 f0 = *(const bf16x8*)p1;
            bf16x8 f1 = *(const bf16x8*)(p1 + 8);
            for (int k = 0; k < 8; k++) {
                a[k]     += bf16_bits_to_f32((unsigned short)e0[k]);
                a[k + 8] += bf16_bits_to_f32((unsigned short)e1[k]);
                b[k]     += bf16_bits_to_f32((unsigned short)f0[k]);
                b[k + 8] += bf16_bits_to_f32((unsigned short)f1[k]);
            }
        }
        if (j < j1) {
            int r0 = srow[j];
            const unsigned short* p0 = h + (size_t)r0 * 256 + c16;
            bf16x8 e0 = *(const bf16x8*)p0;
            bf16x8 e1 = *(const bf16x8*)(p0 + 8);
            for (int k = 0; k < 8; k++) {
                a[k]     += bf16_bits_to_f32((unsigned short)e0[k]);
                a[k + 8] += bf16_bits_to_f32((unsigned short)e1[k]);
            }
        }
        // combine unroll accumulators + cross-group reduce (lane^16, lane^32)
        for (int k = 0; k < 16; k++) {
            float s = a[k] + b[k];
            s += __shfl_xor(s, 16);
            s += __shfl_xor(s, 32);
            a[k] = s;
        }
        // each lane sigmoids its 4 columns: k in [g*4, g*4+4)
        for (int t = 0; t < 4; t++) {
            float val = a[g * 4 + t] * dc + ((const float*)&bc)[t];
            m[t] += 1.f / (1.f + __expf(-val));
        }
    }
    __shared__ float red[4][256];
    for (int t = 0; t < 4; t++) red[wid][c16 + g * 4 + t] = m[t];
    __syncthreads();
    int d = threadIdx.x;
    partials[(size_t)blockIdx.x * 256 + d] = red[0][d] + red[1][d] + red[2][d] + red[3][d];
}

// ---------------- reduce partials: 2048 rows -> 32 rows ----------------
__global__ void reduceA_kernel(const float* __restrict__ partials, float* __restrict__ p2) {
    int d = threadIdx.x;
    int b = blockIdx.x;
    float s = 0.f;
    int r0 = b * 64;
    for (int r = r0; r < r0 + 64; r++) s += partials[r * 256 + d];
    p2[b * 256 + d] = s;
}

// ---------------- final ----------------
__global__ void final_kernel(const float* __restrict__ p2, const float* __restrict__ wlin,
                             const float* __restrict__ blin, float* __restrict__ out, int N) {
    int d = threadIdx.x;
    float s = 0.f;
    for (int b = 0; b < 32; b++) s += p2[b * 256 + d];
    float x3 = s / (float)N;
    float t = x3 * wlin[d];
    __shared__ float red[256];
    red[d] = t;
    __syncthreads();
    for (int st = 128; st > 0; st >>= 1) {
        if (d < st) red[d] += red[d + st];
        __syncthreads();
    }
    if (d == 0) out[0] = 1.f / (1.f + expf(-(red[0] + blin[0])));
}

extern "C" void kernel_launch(void* const* d_in, const int* in_sizes, int n_in,
                              void* d_out, int out_size, void* d_ws, size_t ws_size,
                              hipStream_t stream) {
    const float* x     = (const float*)d_in[0];
    const int*   ei    = (const int*)d_in[1];
    const float* W     = (const float*)d_in[2];
    const float* bconv = (const float*)d_in[3];
    const float* wlin  = (const float*)d_in[4];
    const float* blin  = (const float*)d_in[5];
    float* out = (float*)d_out;

    int N = in_sizes[0] / 256;
    int E = in_sizes[1] / 2;

    char* ws = (char*)d_ws;
    size_t o = 0;
    auto alloc = [&](size_t bytes) -> char* {
        char* p = ws + o;
        o = (o + bytes + 255) & ~(size_t)255;
        return p;
    };
    int*   cnt     = (int*)alloc((size_t)N * 4);
    int*   off     = (int*)alloc((size_t)(N + 1) * 4);
    int*   cursor  = (int*)alloc((size_t)N * 4);
    float* dis     = (float*)alloc((size_t)N * 4);
    int*   bsums   = (int*)alloc(64 * 4);
    int*   bbase   = (int*)alloc(64 * 4);
    int*   srow    = (int*)alloc((size_t)E * 4);
    unsigned short* Wb = (unsigned short*)alloc(65536 * 2);
    unsigned short* xb = (unsigned short*)alloc((size_t)N * 256 * 2);
    unsigned short* h  = (unsigned short*)alloc((size_t)N * 256 * 2);
    float* partials = (float*)alloc(2048 * 256 * 4);
    float* p2       = (float*)alloc(32 * 256 * 4);

    hipMemsetAsync(cnt, 0, (size_t)N * 4, stream);

    int eb = (E + 255) / 256;
    count_kernel<<<eb, 256, 0, stream>>>(ei + E, cnt, E);

    int nbA = (N + 1023) / 1024;
    scanA_kernel<<<nbA, 256, 0, stream>>>(cnt, off, bsums, N);
    scanB_kernel<<<1, 64, 0, stream>>>(bsums, bbase, nbA);
    scanC_kernel<<<(N + 255) / 256, 256, 0, stream>>>(off, cursor, dis, cnt, bbase, N, E);
    scatter_kernel<<<eb, 256, 0, stream>>>(ei, cursor, srow, E);

    xconv_kernel<<<1024, 256, 0, stream>>>(x, xb, N * 256 / 8);
    wprep_kernel<<<65536 / 256, 256, 0, stream>>>(W, Wb);
    gemm_kernel<<<(N + 63) / 64, 256, 0, stream>>>(xb, Wb, dis, h, N);

    agg_kernel<<<2048, 256, 0, stream>>>(h, off, srow, dis, bconv, partials, N);
    reduceA_kernel<<<32, 256, 0, stream>>>(partials, p2);
    final_kernel<<<1, 256, 0, stream>>>(p2, wlin, blin, out, N);
}